// Round 12
// baseline (6965.565 us; speedup 1.0000x reference)
//
#include <hip/hip_runtime.h>

#define T_STEPS 8192
#define BATCH   128
#define HID     96
#define BT      16                 // batch tile per block
#define NBLK    (BATCH / BT)       // 8 blocks

typedef unsigned int u32;
typedef u32   u32x4 __attribute__((ext_vector_type(4)));
typedef float f32x4 __attribute__((ext_vector_type(4)));
typedef __fp16 h2_t __attribute__((ext_vector_type(2)));

__device__ __forceinline__ u32 pk2(float a, float b) {
    return __builtin_bit_cast(u32, __builtin_amdgcn_cvt_pkrtz(a, b));
}
__device__ __forceinline__ float fdot2u(u32 w, u32 h, float acc) {
    return __builtin_amdgcn_fdot2(__builtin_bit_cast(h2_t, w),
                                  __builtin_bit_cast(h2_t, h), acc, false);
}
__device__ __forceinline__ float fast_sigmoid(float v) {
    return __builtin_amdgcn_rcpf(1.0f + __expf(-v));
}
__device__ __forceinline__ float fast_tanh(float v) {   // 2*sigmoid(2v)-1
    return fmaf(2.0f, __builtin_amdgcn_rcpf(1.0f + __expf(-2.0f * v)), -1.0f);
}

// D = A*B + C ; A from VGPR, B from AGPR (zero read-back), C/D in VGPR.
#define MFMA(ACC, AF, BF) \
    asm("v_mfma_f32_16x16x32_f16 %0, %1, %2, %0" : "+v"(ACC) : "v"(AF), "a"(BF))

// ---- prepack W_hh -> f16 MFMA B-frags, thread-major ----
// worker tid (0..383): u=tid>>6 (wave), l=tid&63. frag f=g*3+s (gate g, K-slice s).
// B[k][n] = W_hh[n][k], n = g*96 + u*16 + (l&15), k = s*32 + (l>>4)*8 + 2r{,+1}.
__global__ void prepack_kernel(const float* __restrict__ W_hh, u32* __restrict__ wpk) {
    const int i = blockIdx.x * blockDim.x + threadIdx.x;   // u32 index
    if (i < 384 * 48) {
        const int r   = i & 3;
        const int u4  = i >> 2;
        const int tid = u4 / 12;
        const int f   = u4 % 12;
        const int g = f / 3, s = f % 3;
        const int l = tid & 63, u = tid >> 6;
        const int n = g * HID + u * 16 + (l & 15);
        const int k = s * 32 + ((l >> 4) & 3) * 8 + 2 * r;
        wpk[i] = pk2(W_hh[n * HID + k], W_hh[n * HID + k + 1]);
    }
}

__global__ __attribute__((amdgpu_flat_work_group_size(448, 448), amdgpu_waves_per_eu(1, 2)))
void lstm_mfma_kernel(const float* __restrict__ x,
                      const float* __restrict__ W_ih,
                      const float* __restrict__ b_ih,
                      const float* __restrict__ b_hh,
                      const float* __restrict__ W_fc,
                      const float* __restrict__ b_fc,
                      const u32x4* __restrict__ wpk4,
                      float* __restrict__ out)
{
    const int bo  = blockIdx.x * BT;
    const int tid = threadIdx.x;      // 0..447: waves 0-5 workers, wave 6 FC+x-stage

    __shared__ __align__(16) __fp16 hbuf[2][BT][104];   // h_seq state, row-pad 104
    __shared__ __align__(16) float  xs[2][BT];          // staged x per step

    for (int i = tid; i < 2 * BT * 104 / 2; i += 448) ((u32*)hbuf)[i] = 0u;
    if (tid < BT) xs[0][tid] = x[bo + tid];
    __syncthreads();

    if (tid < 384) {
        // ---------------- worker: wave u owns units u*16..u*16+15, all 4 gates ----------------
        const int l = tid & 63, u = tid >> 6;
        const int j = u * 16 + (l & 15);            // this lane's unit (epilogue)

        // B-frags: load once, pin into AGPRs (opaque def -> MachineSink/remat impossible).
        const u32x4* wp = wpk4 + tid * 12;
        u32x4 b0 = wp[0], b1 = wp[1], b2  = wp[2],  b3  = wp[3];
        u32x4 b4 = wp[4], b5 = wp[5], b6  = wp[6],  b7  = wp[7];
        u32x4 b8 = wp[8], b9 = wp[9], b10 = wp[10], b11 = wp[11];
        asm volatile("" : "+a"(b0));  asm volatile("" : "+a"(b1));
        asm volatile("" : "+a"(b2));  asm volatile("" : "+a"(b3));
        asm volatile("" : "+a"(b4));  asm volatile("" : "+a"(b5));
        asm volatile("" : "+a"(b6));  asm volatile("" : "+a"(b7));
        asm volatile("" : "+a"(b8));  asm volatile("" : "+a"(b9));
        asm volatile("" : "+a"(b10)); asm volatile("" : "+a"(b11));

        // per-gate x-weights / biases for unit j (pin: tiny, keeps loop load-free)
        f32x4 wih4 = { W_ih[0*HID+j], W_ih[1*HID+j], W_ih[2*HID+j], W_ih[3*HID+j] };
        f32x4 bs4  = { b_ih[0*HID+j] + b_hh[0*HID+j], b_ih[1*HID+j] + b_hh[1*HID+j],
                       b_ih[2*HID+j] + b_hh[2*HID+j], b_ih[3*HID+j] + b_hh[3*HID+j] };
        asm volatile("" : "+v"(wih4)); asm volatile("" : "+v"(bs4));

        f32x4 c = {0.f, 0.f, 0.f, 0.f};             // cell state, 4 batches of unit j

        for (int t = 0; t < T_STEPS; ++t) {
            const int cb = t & 1;
            // A-frags: lane l holds h[batch l&15][k=(l>>4)*8 + s*32 .. +8]
            const __fp16* hrow = &hbuf[cb][l & 15][(l >> 4) * 8];
            const u32x4 a0 = *(const u32x4*)(hrow);
            const u32x4 a1 = *(const u32x4*)(hrow + 32);
            const u32x4 a2 = *(const u32x4*)(hrow + 64);
            const f32x4 xv = *(const f32x4*)&xs[cb][(l >> 4) * 4];

            // C-init = x-projection + biases (per batch r)
            f32x4 acc0 = xv * wih4[0] + bs4[0];
            f32x4 acc1 = xv * wih4[1] + bs4[1];
            f32x4 acc2 = xv * wih4[2] + bs4[2];
            f32x4 acc3 = xv * wih4[3] + bs4[3];

            MFMA(acc0, a0, b0); MFMA(acc1, a0, b3); MFMA(acc2, a0, b6); MFMA(acc3, a0, b9);
            MFMA(acc0, a1, b1); MFMA(acc1, a1, b4); MFMA(acc2, a1, b7); MFMA(acc3, a1, b10);
            MFMA(acc0, a2, b2); MFMA(acc1, a2, b5); MFMA(acc2, a2, b8); MFMA(acc3, a2, b11);
            asm volatile("s_nop 7\n\ts_nop 7\n\ts_nop 7\n\ts_nop 7"); // MFMA->VALU hazard

            // epilogue: acc_g[r] = preact[batch (l>>4)*4+r][gate g of unit j]
            const int nb = cb ^ 1;
            #pragma unroll
            for (int r = 0; r < 4; ++r) {
                const float gi = fast_sigmoid(acc0[r]);
                const float gf = fast_sigmoid(acc1[r]);
                const float gg = fast_tanh(acc2[r]);
                const float go = fast_sigmoid(acc3[r]);
                c[r] = fmaf(gf, c[r], gi * gg);
                const float hn = go * fast_tanh(c[r]);
                hbuf[nb][(l >> 4) * 4 + r][j] = (__fp16)hn;
            }
            __syncthreads();
        }
    } else {
        // ---------------- FC wave: x staging + deferred output ----------------
        const int lane = tid - 384;                 // 0..63
        const int m = lane >> 2, p = lane & 3;      // batch m, quarter p
        const float bfc = b_fc[0];
        u32 wf[12];
        #pragma unroll
        for (int r = 0; r < 12; ++r) wf[r] = pk2(W_fc[p * 24 + 2 * r], W_fc[p * 24 + 2 * r + 1]);

        for (int t = 0; t < T_STEPS; ++t) {
            if (t > 0) {
                const float xprev = xs[(t - 1) & 1][m];        // read BEFORE staging overwrite
                const u32x4* hb = (const u32x4*)&hbuf[t & 1][m][p * 24];
                const u32x4 h0 = hb[0], h1 = hb[1], h2 = hb[2];
                float s = 0.0f;
                s = fdot2u(wf[0], h0[0], s); s = fdot2u(wf[1],  h0[1], s);
                s = fdot2u(wf[2], h0[2], s); s = fdot2u(wf[3],  h0[3], s);
                s = fdot2u(wf[4], h1[0], s); s = fdot2u(wf[5],  h1[1], s);
                s = fdot2u(wf[6], h1[2], s); s = fdot2u(wf[7],  h1[3], s);
                s = fdot2u(wf[8], h2[0], s); s = fdot2u(wf[9],  h2[1], s);
                s = fdot2u(wf[10],h2[2], s); s = fdot2u(wf[11], h2[3], s);
                s += __shfl_xor(s, 1); s += __shfl_xor(s, 2);
                if (p == 0) out[(t - 1) * BATCH + bo + m] = s + bfc + xprev;
            }
            if (lane < BT) {                        // stage x[t+1]
                const int tn = (t + 1 < T_STEPS) ? (t + 1) : (T_STEPS - 1);
                xs[(t + 1) & 1][lane] = x[tn * BATCH + bo + lane];
            }
            __syncthreads();
        }
        {   // final out[T-1]: h_seq[T-1] lives in hbuf[T&1]
            const float xlast = xs[(T_STEPS - 1) & 1][m];
            const u32x4* hb = (const u32x4*)&hbuf[T_STEPS & 1][m][p * 24];
            const u32x4 h0 = hb[0], h1 = hb[1], h2 = hb[2];
            float s = 0.0f;
            s = fdot2u(wf[0], h0[0], s); s = fdot2u(wf[1],  h0[1], s);
            s = fdot2u(wf[2], h0[2], s); s = fdot2u(wf[3],  h0[3], s);
            s = fdot2u(wf[4], h1[0], s); s = fdot2u(wf[5],  h1[1], s);
            s = fdot2u(wf[6], h1[2], s); s = fdot2u(wf[7],  h1[3], s);
            s = fdot2u(wf[8], h2[0], s); s = fdot2u(wf[9],  h2[1], s);
            s = fdot2u(wf[10],h2[2], s); s = fdot2u(wf[11], h2[3], s);
            s += __shfl_xor(s, 1); s += __shfl_xor(s, 2);
            if (p == 0) out[(T_STEPS - 1) * BATCH + bo + m] = s + bfc + xlast;
        }
    }
}

extern "C" void kernel_launch(void* const* d_in, const int* in_sizes, int n_in,
                              void* d_out, int out_size, void* d_ws, size_t ws_size,
                              hipStream_t stream) {
    (void)in_sizes; (void)n_in; (void)out_size; (void)ws_size;
    const float* x    = (const float*)d_in[0];
    const float* W_ih = (const float*)d_in[1];
    const float* W_hh = (const float*)d_in[2];
    const float* b_ih = (const float*)d_in[3];
    const float* b_hh = (const float*)d_in[4];
    const float* W_fc = (const float*)d_in[5];
    const float* b_fc = (const float*)d_in[6];
    float* out = (float*)d_out;
    u32* wpk = (u32*)d_ws;                          // 384*48 u32 = 73728 B

    prepack_kernel<<<dim3((384 * 48 + 255) / 256), dim3(256), 0, stream>>>(W_hh, wpk);

    lstm_mfma_kernel<<<dim3(NBLK), dim3(448), 0, stream>>>(
        x, W_ih, b_ih, b_hh, W_fc, b_fc, (const u32x4*)wpk, out);
}

// Round 13
// 6694.702 us; speedup vs baseline: 1.0405x; 1.0405x over previous
//
#include <hip/hip_runtime.h>

#define T_STEPS 8192
#define BATCH   128
#define HID     96
#define BT      16                 // batch tile per block
#define NBLK    (BATCH / BT)       // 8 blocks

typedef unsigned int u32;
typedef u32   u32x4 __attribute__((ext_vector_type(4)));
typedef float f32x4 __attribute__((ext_vector_type(4)));
typedef __fp16 h2_t __attribute__((ext_vector_type(2)));

__device__ __forceinline__ u32 pk2(float a, float b) {
    return __builtin_bit_cast(u32, __builtin_amdgcn_cvt_pkrtz(a, b));
}
__device__ __forceinline__ float fdot2u(u32 w, u32 h, float acc) {
    return __builtin_amdgcn_fdot2(__builtin_bit_cast(h2_t, w),
                                  __builtin_bit_cast(h2_t, h), acc, false);
}
__device__ __forceinline__ float fast_sigmoid(float v) {
    return __builtin_amdgcn_rcpf(1.0f + __expf(-v));
}
__device__ __forceinline__ float fast_tanh(float v) {   // 2*sigmoid(2v)-1
    return fmaf(2.0f, __builtin_amdgcn_rcpf(1.0f + __expf(-2.0f * v)), -1.0f);
}

// D = A*B + C ; A from VGPR, B from AGPR (zero read-back), C/D in VGPR.
#define MFMA(ACC, AF, BF) \
    asm("v_mfma_f32_16x16x32_f16 %0, %1, %2, %0" : "+v"(ACC) : "v"(AF), "a"(BF))

// ---- prepack W_hh -> f16 MFMA B-frags, thread-major (R12 layout, verified) ----
__global__ void prepack_kernel(const float* __restrict__ W_hh, u32* __restrict__ wpk) {
    const int i = blockIdx.x * blockDim.x + threadIdx.x;   // u32 index
    if (i < 384 * 48) {
        const int r   = i & 3;
        const int u4  = i >> 2;
        const int tid = u4 / 12;
        const int f   = u4 % 12;
        const int g = f / 3, s = f % 3;
        const int l = tid & 63, u = tid >> 6;
        const int n = g * HID + u * 16 + (l & 15);
        const int k = s * 32 + ((l >> 4) & 3) * 8 + 2 * r;
        wpk[i] = pk2(W_hh[n * HID + k], W_hh[n * HID + k + 1]);
    }
}

__global__ __attribute__((amdgpu_flat_work_group_size(448, 448), amdgpu_waves_per_eu(1, 2)))
void lstm_mfma_kernel(const float* __restrict__ x,
                      const float* __restrict__ W_ih,
                      const float* __restrict__ b_ih,
                      const float* __restrict__ b_hh,
                      const float* __restrict__ W_fc,
                      const float* __restrict__ b_fc,
                      const u32x4* __restrict__ wpk4,
                      float* __restrict__ out)
{
    const int bo  = blockIdx.x * BT;
    const int tid = threadIdx.x;      // 0..447: waves 0-5 workers, wave 6 FC+x-stage

    __shared__ __align__(16) __fp16 hbuf[2][BT][104];   // h_seq state, row-pad 104
    __shared__ __align__(16) float  xs[2][BT];          // staged x per step

    for (int i = tid; i < 2 * BT * 104 / 2; i += 448) ((u32*)hbuf)[i] = 0u;
    if (tid < BT) xs[0][tid] = x[bo + tid];
    __syncthreads();

    if (tid < 384) {
        // ---------------- worker: wave u owns units u*16..u*16+15, all 4 gates ----------------
        const int l = tid & 63, u = tid >> 6;
        const int j = u * 16 + (l & 15);            // this lane's unit (epilogue)

        // B-frags: load once, pin into AGPRs (opaque def -> MachineSink/remat impossible).
        const u32x4* wp = wpk4 + tid * 12;
        u32x4 b0 = wp[0], b1 = wp[1], b2  = wp[2],  b3  = wp[3];
        u32x4 b4 = wp[4], b5 = wp[5], b6  = wp[6],  b7  = wp[7];
        u32x4 b8 = wp[8], b9 = wp[9], b10 = wp[10], b11 = wp[11];
        asm volatile("" : "+a"(b0));  asm volatile("" : "+a"(b1));
        asm volatile("" : "+a"(b2));  asm volatile("" : "+a"(b3));
        asm volatile("" : "+a"(b4));  asm volatile("" : "+a"(b5));
        asm volatile("" : "+a"(b6));  asm volatile("" : "+a"(b7));
        asm volatile("" : "+a"(b8));  asm volatile("" : "+a"(b9));
        asm volatile("" : "+a"(b10)); asm volatile("" : "+a"(b11));

        // per-gate x-weights / biases for unit j (pinned; loop stays load-free)
        f32x4 wih4 = { W_ih[0*HID+j], W_ih[1*HID+j], W_ih[2*HID+j], W_ih[3*HID+j] };
        f32x4 bs4  = { b_ih[0*HID+j] + b_hh[0*HID+j], b_ih[1*HID+j] + b_hh[1*HID+j],
                       b_ih[2*HID+j] + b_hh[2*HID+j], b_ih[3*HID+j] + b_hh[3*HID+j] };
        asm volatile("" : "+v"(wih4)); asm volatile("" : "+v"(bs4));

        f32x4 c = {0.f, 0.f, 0.f, 0.f};             // cell state, 4 batches of unit j

        for (int t = 0; t < T_STEPS; ++t) {
            const int cb = t & 1;
            // A-frags: lane l holds h[batch l&15][k=(l>>4)*8 + s*32 .. +8]
            const __fp16* hrow = &hbuf[cb][l & 15][(l >> 4) * 8];
            const u32x4 a0 = *(const u32x4*)(hrow);
            const u32x4 a1 = *(const u32x4*)(hrow + 32);
            const u32x4 a2 = *(const u32x4*)(hrow + 64);
            const f32x4 xv = *(const f32x4*)&xs[cb][(l >> 4) * 4];

            // C-init = x-projection + biases (per batch r)
            f32x4 acc0 = xv * wih4[0] + bs4[0];
            f32x4 acc1 = xv * wih4[1] + bs4[1];
            f32x4 acc2 = xv * wih4[2] + bs4[2];
            f32x4 acc3 = xv * wih4[3] + bs4[3];

            MFMA(acc0, a0, b0); MFMA(acc1, a0, b3); MFMA(acc2, a0, b6); MFMA(acc3, a0, b9);
            MFMA(acc0, a1, b1); MFMA(acc1, a1, b4); MFMA(acc2, a1, b7); MFMA(acc3, a1, b10);
            MFMA(acc0, a2, b2); MFMA(acc1, a2, b5); MFMA(acc2, a2, b8); MFMA(acc3, a2, b11);
            asm volatile("s_nop 7\n\ts_nop 7");     // MFMA->VALU hazard guard

            // epilogue: acc_g[r] = preact[batch (l>>4)*4+r][gate g of unit j]
            const int nb = cb ^ 1;
            #pragma unroll
            for (int r = 0; r < 4; ++r) {
                const float gi = fast_sigmoid(acc0[r]);
                const float gf = fast_sigmoid(acc1[r]);
                const float gg = fast_tanh(acc2[r]);
                const float go = fast_sigmoid(acc3[r]);
                c[r] = fmaf(gf, c[r], gi * gg);
                const float hn = go * fast_tanh(c[r]);
                hbuf[nb][(l >> 4) * 4 + r][j] = (__fp16)hn;
            }
            __syncthreads();
        }
    } else {
        // ------------ FC wave: x staging (register-pipelined) + deferred output ------------
        const int lane = tid - 384;                 // 0..63
        const int m = lane >> 2, p = lane & 3;      // batch m, quarter p
        const int ll = lane & 15;                   // staging lane (dup x4, benign)
        const float bfc = b_fc[0];
        u32 wf[12];
        #pragma unroll
        for (int r = 0; r < 12; ++r) wf[r] = pk2(W_fc[p * 24 + 2 * r], W_fc[p * 24 + 2 * r + 1]);

        // x pipeline, distance 2: xrA = x[t+1], xrB = x[t+2] (in flight)
        float xrA = x[1 * BATCH + bo + ll];
        float xrB = x[2 * BATCH + bo + ll];

        for (int t = 0; t < T_STEPS; ++t) {
            if (t > 0) {
                const float xprev = xs[(t - 1) & 1][m];        // read BEFORE overwrite
                const u32x4* hb = (const u32x4*)&hbuf[t & 1][m][p * 24];
                const u32x4 h0 = hb[0], h1 = hb[1], h2 = hb[2];
                float s0 = 0.0f, s1 = 0.0f, s2 = 0.0f;         // 3 independent chains
                s0 = fdot2u(wf[0], h0[0], s0); s0 = fdot2u(wf[1],  h0[1], s0);
                s0 = fdot2u(wf[2], h0[2], s0); s0 = fdot2u(wf[3],  h0[3], s0);
                s1 = fdot2u(wf[4], h1[0], s1); s1 = fdot2u(wf[5],  h1[1], s1);
                s1 = fdot2u(wf[6], h1[2], s1); s1 = fdot2u(wf[7],  h1[3], s1);
                s2 = fdot2u(wf[8], h2[0], s2); s2 = fdot2u(wf[9],  h2[1], s2);
                s2 = fdot2u(wf[10],h2[2], s2); s2 = fdot2u(wf[11], h2[3], s2);
                float s = (s0 + s1) + s2;
                s += __shfl_xor(s, 1); s += __shfl_xor(s, 2);
                if (p == 0) out[(t - 1) * BATCH + bo + m] = s + bfc + xprev;
            }
            // stage x[t+1] from REGISTER (no latency on the barrier path), then
            // shift the pipeline and issue the load for x[t+3] (2-step tolerance).
            if (lane < BT) xs[(t + 1) & 1][lane] = xrA;
            xrA = xrB;
            const int tn = (t + 3 < T_STEPS) ? (t + 3) : (T_STEPS - 1);
            xrB = x[tn * BATCH + bo + ll];
            __syncthreads();
        }
        {   // final out[T-1]: h_seq[T-1] lives in hbuf[T&1]
            const float xlast = xs[(T_STEPS - 1) & 1][m];
            const u32x4* hb = (const u32x4*)&hbuf[T_STEPS & 1][m][p * 24];
            const u32x4 h0 = hb[0], h1 = hb[1], h2 = hb[2];
            float s0 = 0.0f, s1 = 0.0f, s2 = 0.0f;
            s0 = fdot2u(wf[0], h0[0], s0); s0 = fdot2u(wf[1],  h0[1], s0);
            s0 = fdot2u(wf[2], h0[2], s0); s0 = fdot2u(wf[3],  h0[3], s0);
            s1 = fdot2u(wf[4], h1[0], s1); s1 = fdot2u(wf[5],  h1[1], s1);
            s1 = fdot2u(wf[6], h1[2], s1); s1 = fdot2u(wf[7],  h1[3], s1);
            s2 = fdot2u(wf[8], h2[0], s2); s2 = fdot2u(wf[9],  h2[1], s2);
            s2 = fdot2u(wf[10],h2[2], s2); s2 = fdot2u(wf[11], h2[3], s2);
            float s = (s0 + s1) + s2;
            s += __shfl_xor(s, 1); s += __shfl_xor(s, 2);
            if (p == 0) out[(T_STEPS - 1) * BATCH + bo + m] = s + bfc + xlast;
        }
    }
}

extern "C" void kernel_launch(void* const* d_in, const int* in_sizes, int n_in,
                              void* d_out, int out_size, void* d_ws, size_t ws_size,
                              hipStream_t stream) {
    (void)in_sizes; (void)n_in; (void)out_size; (void)ws_size;
    const float* x    = (const float*)d_in[0];
    const float* W_ih = (const float*)d_in[1];
    const float* W_hh = (const float*)d_in[2];
    const float* b_ih = (const float*)d_in[3];
    const float* b_hh = (const float*)d_in[4];
    const float* W_fc = (const float*)d_in[5];
    const float* b_fc = (const float*)d_in[6];
    float* out = (float*)d_out;
    u32* wpk = (u32*)d_ws;                          // 384*48 u32 = 73728 B

    prepack_kernel<<<dim3((384 * 48 + 255) / 256), dim3(256), 0, stream>>>(W_hh, wpk);

    lstm_mfma_kernel<<<dim3(NBLK), dim3(448), 0, stream>>>(
        x, W_ih, b_ih, b_hh, W_fc, b_fc, (const u32x4*)wpk, out);
}